// Round 1
// baseline (167.918 us; speedup 1.0000x reference)
//
#include <hip/hip_runtime.h>
#include <math.h>

#define H 256
#define NHD 4
#define DH 64
#define BM 8

// ---------------------------------------------------------------------------
// seg is sorted; seg_start[b] = first node index with seg >= b, seg_start[B]=N
// ---------------------------------------------------------------------------
__global__ void seg_bounds_kernel(const int* __restrict__ seg,
                                  int* __restrict__ seg_start,
                                  int N, int B) {
    int n = blockIdx.x * blockDim.x + threadIdx.x;
    if (n >= N) return;
    int s = seg[n];
    if (n == 0) {
        for (int b = 0; b <= s; ++b) seg_start[b] = 0;
    } else {
        int sp = seg[n - 1];
        for (int b = sp + 1; b <= s; ++b) seg_start[b] = n;
    }
    if (n == N - 1) {
        for (int b = s + 1; b <= B; ++b) seg_start[b] = N;
    }
}

// ---------------------------------------------------------------------------
// 256x256 fp32 transpose (for coalesced weight access in the MLP kernel)
// ---------------------------------------------------------------------------
__global__ void transpose256_kernel(const float* __restrict__ in,
                                    float* __restrict__ out) {
    __shared__ float tile[32][33];
    int bx = blockIdx.x & 7, by = blockIdx.x >> 3;
    int tx = threadIdx.x & 31, ty = threadIdx.x >> 5;  // 32x8 threads
#pragma unroll
    for (int r = 0; r < 32; r += 8)
        tile[ty + r][tx] = in[(by * 32 + ty + r) * H + bx * 32 + tx];
    __syncthreads();
#pragma unroll
    for (int r = 0; r < 32; r += 8)
        out[(bx * 32 + ty + r) * H + by * 32 + tx] = tile[tx][ty + r];
}

// ---------------------------------------------------------------------------
// Main pool: one block (4 waves) per segment. Each wave processes whole nodes
// (64 lanes x float4 = 256 floats = 1 row), online softmax per wave, merged
// across waves at the end. Single pass over node_feats.
// ---------------------------------------------------------------------------
__launch_bounds__(256, 8)
__global__ void pool_kernel(const float* __restrict__ node_feats,
                            const float* __restrict__ g_feats,
                            const float* __restrict__ degree,
                            const float* __restrict__ attn,
                            const int* __restrict__ seg_start,
                            float* __restrict__ he_out) {
    const int b = blockIdx.x;
    const int tid = threadIdx.x;
    const int wave = tid >> 6;
    const int lane = tid & 63;
    const int start = seg_start[b];
    const int end = seg_start[b + 1];

    // lane owns features [lane*4, lane*4+4); head = lane>>4
    float4 g4 = *reinterpret_cast<const float4*>(g_feats + (size_t)b * H + lane * 4);
    float4 a4 = *reinterpret_cast<const float4*>(attn + lane * 4);

    // per-head dot(g, attn) — constant over the segment
    float gz = g4.x * a4.x + g4.y * a4.y + g4.z * a4.z + g4.w * a4.w;
#pragma unroll
    for (int s = 1; s < 16; s <<= 1) gz += __shfl_xor(gz, s, 64);

    float m = -INFINITY, lsum = 0.0f;
    float4 acc = make_float4(0.f, 0.f, 0.f, 0.f);

    for (int n = start + wave; n < end; n += 4) {
        float4 v = *reinterpret_cast<const float4*>(node_feats + (size_t)n * H + lane * 4);
        float p = v.x * a4.x + v.y * a4.y + v.z * a4.z + v.w * a4.w;
#pragma unroll
        for (int s = 1; s < 16; s <<= 1) p += __shfl_xor(p, s, 64);
        float z = (p + gz) * degree[n];
        float mnew = fmaxf(m, z);
        float f = __expf(m - mnew);   // exp(-inf)=0 on first node; 1 if m stays max
        float e = __expf(z - mnew);
        lsum = lsum * f + e;
        acc.x = acc.x * f + e * (v.x + g4.x);
        acc.y = acc.y * f + e * (v.y + g4.y);
        acc.z = acc.z * f + e * (v.z + g4.z);
        acc.w = acc.w * f + e * (v.w + g4.w);
        m = mnew;
    }

    // merge the 4 waves' (m, l, acc)
    __shared__ float sm[4][NHD];
    __shared__ float sl[4][NHD];
    __shared__ float sacc[4][H];
    const int head = lane >> 4;
    if ((lane & 15) == 0) { sm[wave][head] = m; sl[wave][head] = lsum; }
    *reinterpret_cast<float4*>(&sacc[wave][lane * 4]) = acc;
    __syncthreads();

    const int h = tid >> 6;  // head of feature `tid`
    float mstar = fmaxf(fmaxf(sm[0][h], sm[1][h]), fmaxf(sm[2][h], sm[3][h]));
    if (!(mstar > -INFINITY)) mstar = 0.0f;  // empty-segment guard (ref: zmax->0)
    float denom = 0.0f, hev = 0.0f;
#pragma unroll
    for (int w = 0; w < 4; ++w) {
        float fw = __expf(sm[w][h] - mstar);  // exp(-inf)=0 for idle waves
        denom += sl[w][h] * fw;
        hev += sacc[w][tid] * fw;
    }
    he_out[(size_t)b * H + tid] = hev / fmaxf(denom, 1e-12f);
}

// ---------------------------------------------------------------------------
// Fused 2-layer MLP + residual: h2 = relu(he@W1T+b1)@W2T + b2 + g
// BM=8 rows per block; thread t owns output column t; W pre-transposed so
// weight loads are coalesced (and L2-resident: 256 KB each).
// ---------------------------------------------------------------------------
__launch_bounds__(256, 4)
__global__ void mlp_kernel(const float* __restrict__ he,
                           const float* __restrict__ W1T,
                           const float* __restrict__ b1,
                           const float* __restrict__ W2T,
                           const float* __restrict__ b2,
                           const float* __restrict__ g_feats,
                           float* __restrict__ out) {
    __shared__ float hbuf[BM][H];
    __shared__ float h1buf[BM][H];
    const int tid = threadIdx.x;
    const size_t row0 = (size_t)blockIdx.x * BM;

#pragma unroll
    for (int i = 0; i < BM; ++i)
        hbuf[i][tid] = he[(row0 + i) * H + tid];
    __syncthreads();

    float acc[BM];
#pragma unroll
    for (int i = 0; i < BM; ++i) acc[i] = 0.f;
    for (int k = 0; k < H; k += 4) {
        float w0 = W1T[(size_t)(k + 0) * H + tid];
        float w1 = W1T[(size_t)(k + 1) * H + tid];
        float w2 = W1T[(size_t)(k + 2) * H + tid];
        float w3 = W1T[(size_t)(k + 3) * H + tid];
#pragma unroll
        for (int i = 0; i < BM; ++i) {
            float4 hv = *reinterpret_cast<const float4*>(&hbuf[i][k]);
            acc[i] += hv.x * w0 + hv.y * w1 + hv.z * w2 + hv.w * w3;
        }
    }
    float bb1 = b1[tid];
#pragma unroll
    for (int i = 0; i < BM; ++i) h1buf[i][tid] = fmaxf(acc[i] + bb1, 0.f);
    __syncthreads();

#pragma unroll
    for (int i = 0; i < BM; ++i) acc[i] = 0.f;
    for (int k = 0; k < H; k += 4) {
        float w0 = W2T[(size_t)(k + 0) * H + tid];
        float w1 = W2T[(size_t)(k + 1) * H + tid];
        float w2 = W2T[(size_t)(k + 2) * H + tid];
        float w3 = W2T[(size_t)(k + 3) * H + tid];
#pragma unroll
        for (int i = 0; i < BM; ++i) {
            float4 hv = *reinterpret_cast<const float4*>(&h1buf[i][k]);
            acc[i] += hv.x * w0 + hv.y * w1 + hv.z * w2 + hv.w * w3;
        }
    }
    float bb2 = b2[tid];
#pragma unroll
    for (int i = 0; i < BM; ++i)
        out[(row0 + i) * H + tid] = acc[i] + bb2 + g_feats[(row0 + i) * H + tid];
}

// ---------------------------------------------------------------------------
extern "C" void kernel_launch(void* const* d_in, const int* in_sizes, int n_in,
                              void* d_out, int out_size, void* d_ws, size_t ws_size,
                              hipStream_t stream) {
    const float* node_feats = (const float*)d_in[0];
    const float* g_feats    = (const float*)d_in[1];
    const float* degree     = (const float*)d_in[2];
    const int*   seg        = (const int*)d_in[3];
    const float* attn       = (const float*)d_in[4];
    const float* W1         = (const float*)d_in[5];
    const float* b1         = (const float*)d_in[6];
    const float* W2         = (const float*)d_in[7];
    const float* b2         = (const float*)d_in[8];
    float* out = (float*)d_out;

    const int N = in_sizes[3];          // seg has N entries
    const int B = in_sizes[1] / H;      // g_feats is [B, H]

    // workspace layout
    char* ws = (char*)d_ws;
    int*   seg_start = (int*)ws;                              // (B+1) ints < 32 KB
    float* W1T = (float*)(ws + 32768);                        // 256 KB
    float* W2T = (float*)(ws + 32768 + H * H * 4);            // 256 KB
    float* he  = (float*)(ws + 32768 + 2 * H * H * 4);        // B*H floats = 4 MB

    seg_bounds_kernel<<<(N + 255) / 256, 256, 0, stream>>>(seg, seg_start, N, B);
    transpose256_kernel<<<64, 256, 0, stream>>>(W1, W1T);
    transpose256_kernel<<<64, 256, 0, stream>>>(W2, W2T);
    pool_kernel<<<B, 256, 0, stream>>>(node_feats, g_feats, degree, attn, seg_start, he);
    mlp_kernel<<<B / BM, 256, 0, stream>>>(he, W1T, b1, W2T, b2, g_feats, out);
}

// Round 2
// 139.063 us; speedup vs baseline: 1.2075x; 1.2075x over previous
//
#include <hip/hip_runtime.h>
#include <math.h>

#define H 256
#define NHD 4
#define BM 8

typedef float f32x4 __attribute__((ext_vector_type(4)));

// ---------------------------------------------------------------------------
// Transpose both 256x256 weight matrices in one launch (blocks 0-63: W1,
// blocks 64-127: W2). Coalesced weight access for the MLP kernel.
// ---------------------------------------------------------------------------
__global__ void transpose2_kernel(const float* __restrict__ W1,
                                  const float* __restrict__ W2,
                                  float* __restrict__ W1T,
                                  float* __restrict__ W2T) {
    __shared__ float tile[32][33];
    const int which = blockIdx.x >> 6;
    const float* in = which ? W2 : W1;
    float* out = which ? W2T : W1T;
    const int blk = blockIdx.x & 63;
    const int bx = blk & 7, by = blk >> 3;
    const int tx = threadIdx.x & 31, ty = threadIdx.x >> 5;  // 32x8
#pragma unroll
    for (int r = 0; r < 32; r += 8)
        tile[ty + r][tx] = in[(by * 32 + ty + r) * H + bx * 32 + tx];
    __syncthreads();
#pragma unroll
    for (int r = 0; r < 32; r += 8)
        out[(bx * 32 + ty + r) * H + by * 32 + tx] = tile[tx][ty + r];
}

// ---------------------------------------------------------------------------
// Pool: one block (4 waves) per segment. Each wave processes 4 consecutive
// node rows per iteration (4 KB contiguous, 4 loads in flight), computes a
// 4-node mini-softmax with parallel exps, then merges once into the running
// online-softmax state. Segment bounds by in-kernel binary search (seg is
// sorted). Single pass over node_feats, nontemporal (read-once stream).
// ---------------------------------------------------------------------------
__launch_bounds__(256, 8)
__global__ void pool_kernel(const float* __restrict__ node_feats,
                            const float* __restrict__ g_feats,
                            const float* __restrict__ degree,
                            const float* __restrict__ attn,
                            const int* __restrict__ seg,
                            int N,
                            float* __restrict__ he_out) {
    const int b = blockIdx.x;
    const int tid = threadIdx.x;
    const int wave = tid >> 6;
    const int lane = tid & 63;

    __shared__ int sb[2];
    if (tid < 2) {
        const int target = b + tid;  // first index with seg[i] >= target
        int lo = 0, hi = N;
        while (lo < hi) {
            int mid = (lo + hi) >> 1;
            if (seg[mid] < target) lo = mid + 1; else hi = mid;
        }
        sb[tid] = lo;
    }
    __syncthreads();
    const int start = sb[0];
    const int end = sb[1];

    // lane owns features [lane*4, lane*4+4); head = lane>>4
    const float4 g4 = *reinterpret_cast<const float4*>(g_feats + (size_t)b * H + lane * 4);
    const float4 a4 = *reinterpret_cast<const float4*>(attn + lane * 4);

    // per-head dot(g, attn) — constant over the segment
    float gz = g4.x * a4.x + g4.y * a4.y + g4.z * a4.z + g4.w * a4.w;
#pragma unroll
    for (int s = 1; s < 16; s <<= 1) gz += __shfl_xor(gz, s, 64);

    float m = -INFINITY, lsum = 0.0f;
    float4 acc = make_float4(0.f, 0.f, 0.f, 0.f);

    int n0 = start + wave * 4;
    for (; n0 + 4 <= end; n0 += 16) {
        const float* rp = node_feats + (size_t)n0 * H + lane * 4;
        f32x4 v0 = __builtin_nontemporal_load(reinterpret_cast<const f32x4*>(rp));
        f32x4 v1 = __builtin_nontemporal_load(reinterpret_cast<const f32x4*>(rp + H));
        f32x4 v2 = __builtin_nontemporal_load(reinterpret_cast<const f32x4*>(rp + 2 * H));
        f32x4 v3 = __builtin_nontemporal_load(reinterpret_cast<const f32x4*>(rp + 3 * H));
        const float d0 = degree[n0], d1 = degree[n0 + 1];
        const float d2 = degree[n0 + 2], d3 = degree[n0 + 3];

        float p0 = v0[0] * a4.x + v0[1] * a4.y + v0[2] * a4.z + v0[3] * a4.w;
        float p1 = v1[0] * a4.x + v1[1] * a4.y + v1[2] * a4.z + v1[3] * a4.w;
        float p2 = v2[0] * a4.x + v2[1] * a4.y + v2[2] * a4.z + v2[3] * a4.w;
        float p3 = v3[0] * a4.x + v3[1] * a4.y + v3[2] * a4.z + v3[3] * a4.w;
#pragma unroll
        for (int s = 1; s < 16; s <<= 1) {
            p0 += __shfl_xor(p0, s, 64);
            p1 += __shfl_xor(p1, s, 64);
            p2 += __shfl_xor(p2, s, 64);
            p3 += __shfl_xor(p3, s, 64);
        }
        const float z0 = (p0 + gz) * d0, z1 = (p1 + gz) * d1;
        const float z2 = (p2 + gz) * d2, z3 = (p3 + gz) * d3;

        // 4-node mini-softmax (parallel exps)
        const float mz = fmaxf(fmaxf(z0, z1), fmaxf(z2, z3));
        const float e0 = __expf(z0 - mz), e1 = __expf(z1 - mz);
        const float e2 = __expf(z2 - mz), e3 = __expf(z3 - mz);
        const float ls = e0 + e1 + e2 + e3;
        const float ax = e0 * v0[0] + e1 * v1[0] + e2 * v2[0] + e3 * v3[0] + ls * g4.x;
        const float ay = e0 * v0[1] + e1 * v1[1] + e2 * v2[1] + e3 * v3[1] + ls * g4.y;
        const float az = e0 * v0[2] + e1 * v1[2] + e2 * v2[2] + e3 * v3[2] + ls * g4.z;
        const float aw = e0 * v0[3] + e1 * v1[3] + e2 * v2[3] + e3 * v3[3] + ls * g4.w;

        // one merge per 4 nodes
        const float mnew = fmaxf(m, mz);
        const float fo = __expf(m - mnew);   // 0 on first batch (m=-inf)
        const float fn = __expf(mz - mnew);
        lsum = lsum * fo + ls * fn;
        acc.x = acc.x * fo + ax * fn;
        acc.y = acc.y * fo + ay * fn;
        acc.z = acc.z * fo + az * fn;
        acc.w = acc.w * fo + aw * fn;
        m = mnew;
    }
    // remainder (<4 nodes for this wave)
    const int nend = (n0 + 4 < end) ? (n0 + 4) : end;
    for (int n = n0; n < nend; ++n) {
        const float* rp = node_feats + (size_t)n * H + lane * 4;
        f32x4 v = __builtin_nontemporal_load(reinterpret_cast<const f32x4*>(rp));
        float p = v[0] * a4.x + v[1] * a4.y + v[2] * a4.z + v[3] * a4.w;
#pragma unroll
        for (int s = 1; s < 16; s <<= 1) p += __shfl_xor(p, s, 64);
        const float z = (p + gz) * degree[n];
        const float mnew = fmaxf(m, z);
        const float fo = __expf(m - mnew);
        const float e = __expf(z - mnew);
        lsum = lsum * fo + e;
        acc.x = acc.x * fo + e * (v[0] + g4.x);
        acc.y = acc.y * fo + e * (v[1] + g4.y);
        acc.z = acc.z * fo + e * (v[2] + g4.z);
        acc.w = acc.w * fo + e * (v[3] + g4.w);
        m = mnew;
    }

    // merge the 4 waves' (m, l, acc)
    __shared__ float sm[4][NHD];
    __shared__ float sl[4][NHD];
    __shared__ float sacc[4][H];
    const int head = lane >> 4;
    if ((lane & 15) == 0) { sm[wave][head] = m; sl[wave][head] = lsum; }
    *reinterpret_cast<float4*>(&sacc[wave][lane * 4]) = acc;
    __syncthreads();

    const int h = tid >> 6;  // head of feature `tid`
    float mstar = fmaxf(fmaxf(sm[0][h], sm[1][h]), fmaxf(sm[2][h], sm[3][h]));
    if (!(mstar > -INFINITY)) mstar = 0.0f;  // empty-segment guard (ref: zmax->0)
    float denom = 0.0f, hev = 0.0f;
#pragma unroll
    for (int w = 0; w < 4; ++w) {
        float fw = __expf(sm[w][h] - mstar);  // exp(-inf)=0 for idle waves
        denom += sl[w][h] * fw;
        hev += sacc[w][tid] * fw;
    }
    he_out[(size_t)b * H + tid] = hev / fmaxf(denom, 1e-12f);
}

// ---------------------------------------------------------------------------
// Fused 2-layer MLP + residual: h2 = relu(he@W1T+b1)@W2T + b2 + g
// ---------------------------------------------------------------------------
__launch_bounds__(256, 4)
__global__ void mlp_kernel(const float* __restrict__ he,
                           const float* __restrict__ W1T,
                           const float* __restrict__ b1,
                           const float* __restrict__ W2T,
                           const float* __restrict__ b2,
                           const float* __restrict__ g_feats,
                           float* __restrict__ out) {
    __shared__ float hbuf[BM][H];
    __shared__ float h1buf[BM][H];
    const int tid = threadIdx.x;
    const size_t row0 = (size_t)blockIdx.x * BM;

#pragma unroll
    for (int i = 0; i < BM; ++i)
        hbuf[i][tid] = he[(row0 + i) * H + tid];
    __syncthreads();

    float acc[BM];
#pragma unroll
    for (int i = 0; i < BM; ++i) acc[i] = 0.f;
    for (int k = 0; k < H; k += 4) {
        float w0 = W1T[(size_t)(k + 0) * H + tid];
        float w1 = W1T[(size_t)(k + 1) * H + tid];
        float w2 = W1T[(size_t)(k + 2) * H + tid];
        float w3 = W1T[(size_t)(k + 3) * H + tid];
#pragma unroll
        for (int i = 0; i < BM; ++i) {
            float4 hv = *reinterpret_cast<const float4*>(&hbuf[i][k]);
            acc[i] += hv.x * w0 + hv.y * w1 + hv.z * w2 + hv.w * w3;
        }
    }
    float bb1 = b1[tid];
#pragma unroll
    for (int i = 0; i < BM; ++i) h1buf[i][tid] = fmaxf(acc[i] + bb1, 0.f);
    __syncthreads();

#pragma unroll
    for (int i = 0; i < BM; ++i) acc[i] = 0.f;
    for (int k = 0; k < H; k += 4) {
        float w0 = W2T[(size_t)(k + 0) * H + tid];
        float w1 = W2T[(size_t)(k + 1) * H + tid];
        float w2 = W2T[(size_t)(k + 2) * H + tid];
        float w3 = W2T[(size_t)(k + 3) * H + tid];
#pragma unroll
        for (int i = 0; i < BM; ++i) {
            float4 hv = *reinterpret_cast<const float4*>(&h1buf[i][k]);
            acc[i] += hv.x * w0 + hv.y * w1 + hv.z * w2 + hv.w * w3;
        }
    }
    float bb2 = b2[tid];
#pragma unroll
    for (int i = 0; i < BM; ++i)
        out[(row0 + i) * H + tid] = acc[i] + bb2 + g_feats[(row0 + i) * H + tid];
}

// ---------------------------------------------------------------------------
extern "C" void kernel_launch(void* const* d_in, const int* in_sizes, int n_in,
                              void* d_out, int out_size, void* d_ws, size_t ws_size,
                              hipStream_t stream) {
    const float* node_feats = (const float*)d_in[0];
    const float* g_feats    = (const float*)d_in[1];
    const float* degree     = (const float*)d_in[2];
    const int*   seg        = (const int*)d_in[3];
    const float* attn       = (const float*)d_in[4];
    const float* W1         = (const float*)d_in[5];
    const float* b1         = (const float*)d_in[6];
    const float* W2         = (const float*)d_in[7];
    const float* b2         = (const float*)d_in[8];
    float* out = (float*)d_out;

    const int N = in_sizes[3];          // seg has N entries
    const int B = in_sizes[1] / H;      // g_feats is [B, H]

    // workspace layout
    char* ws = (char*)d_ws;
    float* W1T = (float*)ws;                           // 256 KB
    float* W2T = (float*)(ws + H * H * 4);             // 256 KB
    float* he  = (float*)(ws + 2 * H * H * 4);         // B*H floats = 4 MB

    transpose2_kernel<<<128, 256, 0, stream>>>(W1, W2, W1T, W2T);
    pool_kernel<<<B, 256, 0, stream>>>(node_feats, g_feats, degree, attn, seg, N, he);
    mlp_kernel<<<B / BM, 256, 0, stream>>>(he, W1T, b1, W2T, b2, g_feats, out);
}

// Round 4
// 112.477 us; speedup vs baseline: 1.4929x; 1.2364x over previous
//
#include <hip/hip_runtime.h>
#include <math.h>

#define H 256
#define NHD 4
#define BM 8

typedef float f32x4 __attribute__((ext_vector_type(4)));

// ---------------------------------------------------------------------------
// seg is sorted; seg_start[b] = first node index with seg >= b, seg_start[B]=N
// ---------------------------------------------------------------------------
__global__ void seg_bounds_kernel(const int* __restrict__ seg,
                                  int* __restrict__ seg_start,
                                  int N, int B) {
    int n = blockIdx.x * blockDim.x + threadIdx.x;
    if (n >= N) return;
    int s = seg[n];
    if (n == 0) {
        for (int b = 0; b <= s; ++b) seg_start[b] = 0;
    } else {
        int sp = seg[n - 1];
        for (int b = sp + 1; b <= s; ++b) seg_start[b] = n;
    }
    if (n == N - 1) {
        for (int b = s + 1; b <= B; ++b) seg_start[b] = N;
    }
}

// ---------------------------------------------------------------------------
// Transpose both 256x256 weight matrices in one launch.
// ---------------------------------------------------------------------------
__global__ void transpose2_kernel(const float* __restrict__ W1,
                                  const float* __restrict__ W2,
                                  float* __restrict__ W1T,
                                  float* __restrict__ W2T) {
    __shared__ float tile[32][33];
    const int which = blockIdx.x >> 6;
    const float* in = which ? W2 : W1;
    float* out = which ? W2T : W1T;
    const int blk = blockIdx.x & 63;
    const int bx = blk & 7, by = blk >> 3;
    const int tx = threadIdx.x & 31, ty = threadIdx.x >> 5;  // 32x8
#pragma unroll
    for (int r = 0; r < 32; r += 8)
        tile[ty + r][tx] = in[(by * 32 + ty + r) * H + bx * 32 + tx];
    __syncthreads();
#pragma unroll
    for (int r = 0; r < 32; r += 8)
        out[(bx * 32 + ty + r) * H + by * 32 + tx] = tile[tx][ty + r];
}

// ---------------------------------------------------------------------------
// Pool: one block (4 waves) per segment. Each wave: 4 consecutive node rows
// per iteration, 4-node mini-softmax, one online-softmax merge per batch.
// Single pass over node_feats (nontemporal read-once stream).
// ---------------------------------------------------------------------------
__launch_bounds__(256, 8)
__global__ void pool_kernel(const float* __restrict__ node_feats,
                            const float* __restrict__ g_feats,
                            const float* __restrict__ degree,
                            const float* __restrict__ attn,
                            const int* __restrict__ seg_start,
                            float* __restrict__ he_out) {
    const int b = blockIdx.x;
    const int tid = threadIdx.x;
    const int wave = tid >> 6;
    const int lane = tid & 63;
    const int start = seg_start[b];
    const int end = seg_start[b + 1];

    const float4 g4 = *reinterpret_cast<const float4*>(g_feats + (size_t)b * H + lane * 4);
    const float4 a4 = *reinterpret_cast<const float4*>(attn + lane * 4);

    float gz = g4.x * a4.x + g4.y * a4.y + g4.z * a4.z + g4.w * a4.w;
#pragma unroll
    for (int s = 1; s < 16; s <<= 1) gz += __shfl_xor(gz, s, 64);

    float m = -INFINITY, lsum = 0.0f;
    float4 acc = make_float4(0.f, 0.f, 0.f, 0.f);

    int n0 = start + wave * 4;
    for (; n0 + 4 <= end; n0 += 16) {
        const float* rp = node_feats + (size_t)n0 * H + lane * 4;
        f32x4 v0 = __builtin_nontemporal_load(reinterpret_cast<const f32x4*>(rp));
        f32x4 v1 = __builtin_nontemporal_load(reinterpret_cast<const f32x4*>(rp + H));
        f32x4 v2 = __builtin_nontemporal_load(reinterpret_cast<const f32x4*>(rp + 2 * H));
        f32x4 v3 = __builtin_nontemporal_load(reinterpret_cast<const f32x4*>(rp + 3 * H));
        const float d0 = degree[n0], d1 = degree[n0 + 1];
        const float d2 = degree[n0 + 2], d3 = degree[n0 + 3];

        float p0 = v0[0] * a4.x + v0[1] * a4.y + v0[2] * a4.z + v0[3] * a4.w;
        float p1 = v1[0] * a4.x + v1[1] * a4.y + v1[2] * a4.z + v1[3] * a4.w;
        float p2 = v2[0] * a4.x + v2[1] * a4.y + v2[2] * a4.z + v2[3] * a4.w;
        float p3 = v3[0] * a4.x + v3[1] * a4.y + v3[2] * a4.z + v3[3] * a4.w;
#pragma unroll
        for (int s = 1; s < 16; s <<= 1) {
            p0 += __shfl_xor(p0, s, 64);
            p1 += __shfl_xor(p1, s, 64);
            p2 += __shfl_xor(p2, s, 64);
            p3 += __shfl_xor(p3, s, 64);
        }
        const float z0 = (p0 + gz) * d0, z1 = (p1 + gz) * d1;
        const float z2 = (p2 + gz) * d2, z3 = (p3 + gz) * d3;

        const float mz = fmaxf(fmaxf(z0, z1), fmaxf(z2, z3));
        const float e0 = __expf(z0 - mz), e1 = __expf(z1 - mz);
        const float e2 = __expf(z2 - mz), e3 = __expf(z3 - mz);
        const float ls = e0 + e1 + e2 + e3;
        const float ax = e0 * v0[0] + e1 * v1[0] + e2 * v2[0] + e3 * v3[0] + ls * g4.x;
        const float ay = e0 * v0[1] + e1 * v1[1] + e2 * v2[1] + e3 * v3[1] + ls * g4.y;
        const float az = e0 * v0[2] + e1 * v1[2] + e2 * v2[2] + e3 * v3[2] + ls * g4.z;
        const float aw = e0 * v0[3] + e1 * v1[3] + e2 * v2[3] + e3 * v3[3] + ls * g4.w;

        const float mnew = fmaxf(m, mz);
        const float fo = __expf(m - mnew);
        const float fn = __expf(mz - mnew);
        lsum = lsum * fo + ls * fn;
        acc.x = acc.x * fo + ax * fn;
        acc.y = acc.y * fo + ay * fn;
        acc.z = acc.z * fo + az * fn;
        acc.w = acc.w * fo + aw * fn;
        m = mnew;
    }
    const int nend = (n0 + 4 < end) ? (n0 + 4) : end;
    for (int n = n0; n < nend; ++n) {
        const float* rp = node_feats + (size_t)n * H + lane * 4;
        f32x4 v = __builtin_nontemporal_load(reinterpret_cast<const f32x4*>(rp));
        float p = v[0] * a4.x + v[1] * a4.y + v[2] * a4.z + v[3] * a4.w;
#pragma unroll
        for (int s = 1; s < 16; s <<= 1) p += __shfl_xor(p, s, 64);
        const float z = (p + gz) * degree[n];
        const float mnew = fmaxf(m, z);
        const float fo = __expf(m - mnew);
        const float e = __expf(z - mnew);
        lsum = lsum * fo + e;
        acc.x = acc.x * fo + e * (v[0] + g4.x);
        acc.y = acc.y * fo + e * (v[1] + g4.y);
        acc.z = acc.z * fo + e * (v[2] + g4.z);
        acc.w = acc.w * fo + e * (v[3] + g4.w);
        m = mnew;
    }

    __shared__ float sm[4][NHD];
    __shared__ float sl[4][NHD];
    __shared__ float sacc[4][H];
    const int head = lane >> 4;
    if ((lane & 15) == 0) { sm[wave][head] = m; sl[wave][head] = lsum; }
    *reinterpret_cast<float4*>(&sacc[wave][lane * 4]) = acc;
    __syncthreads();

    const int h = tid >> 6;
    float mstar = fmaxf(fmaxf(sm[0][h], sm[1][h]), fmaxf(sm[2][h], sm[3][h]));
    if (!(mstar > -INFINITY)) mstar = 0.0f;
    float denom = 0.0f, hev = 0.0f;
#pragma unroll
    for (int w = 0; w < 4; ++w) {
        float fw = __expf(sm[w][h] - mstar);
        denom += sl[w][h] * fw;
        hev += sacc[w][tid] * fw;
    }
    he_out[(size_t)b * H + tid] = hev / fmaxf(denom, 1e-12f);
}

// ---------------------------------------------------------------------------
// MLP v2: wave q owns k-quarter [64q, 64q+64); thread (q,l) owns 4 output
// cols c = l + 64j for BM rows. Each broadcast ds_read_b128 of h[i][k..k+4)
// feeds 16 FMAs -> VALU-bound, not LDS-bound. Cross-wave K reduction via
// 32KB LDS partials buffer.
// ---------------------------------------------------------------------------
__launch_bounds__(256, 4)
__global__ void mlp_kernel(const float* __restrict__ he,
                           const float* __restrict__ W1T,
                           const float* __restrict__ b1,
                           const float* __restrict__ W2T,
                           const float* __restrict__ b2,
                           const float* __restrict__ g_feats,
                           float* __restrict__ out) {
    __shared__ float hbuf[BM][H];       // 8 KB; holds he, then h1
    __shared__ float pacc[4][BM][H];    // 32 KB partials
    const int tid = threadIdx.x;
    const int q = tid >> 6;   // wave = k-quarter
    const int l = tid & 63;
    const size_t row0 = (size_t)blockIdx.x * BM;

#pragma unroll
    for (int i = 0; i < BM; ++i)
        hbuf[i][tid] = he[(row0 + i) * H + tid];
    __syncthreads();

#pragma unroll
    for (int layer = 0; layer < 2; ++layer) {
        const float* WT = layer ? W2T : W1T;
        float acc[BM][4];
#pragma unroll
        for (int i = 0; i < BM; ++i)
#pragma unroll
            for (int j = 0; j < 4; ++j) acc[i][j] = 0.f;

        const int k0 = q * 64;
        for (int s = 0; s < 64; s += 4) {
            const int k = k0 + s;
            float w[4][4];
#pragma unroll
            for (int kk = 0; kk < 4; ++kk)
#pragma unroll
                for (int j = 0; j < 4; ++j)
                    w[kk][j] = WT[(size_t)(k + kk) * H + l + 64 * j];
#pragma unroll
            for (int i = 0; i < BM; ++i) {
                const f32x4 hv = *reinterpret_cast<const f32x4*>(&hbuf[i][k]);
#pragma unroll
                for (int j = 0; j < 4; ++j) {
                    acc[i][j] = __builtin_fmaf(hv[0], w[0][j], acc[i][j]);
                    acc[i][j] = __builtin_fmaf(hv[1], w[1][j], acc[i][j]);
                    acc[i][j] = __builtin_fmaf(hv[2], w[2][j], acc[i][j]);
                    acc[i][j] = __builtin_fmaf(hv[3], w[3][j], acc[i][j]);
                }
            }
        }
#pragma unroll
        for (int i = 0; i < BM; ++i)
#pragma unroll
            for (int j = 0; j < 4; ++j)
                pacc[q][i][l + 64 * j] = acc[i][j];
        __syncthreads();

        // reduce partials: thread handles row i = tid>>5, cols c = (tid&31)+32m
        const int i = tid >> 5;
        const int cbase = tid & 31;
        if (layer == 0) {
#pragma unroll
            for (int mm = 0; mm < 8; ++mm) {
                const int c = cbase + 32 * mm;
                float v = pacc[0][i][c] + pacc[1][i][c] + pacc[2][i][c] + pacc[3][i][c];
                hbuf[i][c] = fmaxf(v + b1[c], 0.f);
            }
        } else {
#pragma unroll
            for (int mm = 0; mm < 8; ++mm) {
                const int c = cbase + 32 * mm;
                float v = pacc[0][i][c] + pacc[1][i][c] + pacc[2][i][c] + pacc[3][i][c];
                out[(row0 + i) * H + c] = v + b2[c] + g_feats[(row0 + i) * H + c];
            }
        }
        __syncthreads();
    }
}

// ---------------------------------------------------------------------------
extern "C" void kernel_launch(void* const* d_in, const int* in_sizes, int n_in,
                              void* d_out, int out_size, void* d_ws, size_t ws_size,
                              hipStream_t stream) {
    const float* node_feats = (const float*)d_in[0];
    const float* g_feats    = (const float*)d_in[1];
    const float* degree     = (const float*)d_in[2];
    const int*   seg        = (const int*)d_in[3];
    const float* attn       = (const float*)d_in[4];
    const float* W1         = (const float*)d_in[5];
    const float* b1         = (const float*)d_in[6];
    const float* W2         = (const float*)d_in[7];
    const float* b2         = (const float*)d_in[8];
    float* out = (float*)d_out;

    const int N = in_sizes[3];
    const int B = in_sizes[1] / H;

    // workspace layout: seg_start needs (B+1)*4 = 16388 bytes -> reserve 32 KB
    char* ws = (char*)d_ws;
    int*   seg_start = (int*)ws;                         // 32 KB reserved
    float* W1T = (float*)(ws + 32768);                   // 256 KB
    float* W2T = (float*)(ws + 32768 + H * H * 4);       // 256 KB
    float* he  = (float*)(ws + 32768 + 2 * H * H * 4);   // 4 MB

    seg_bounds_kernel<<<(N + 255) / 256, 256, 0, stream>>>(seg, seg_start, N, B);
    transpose2_kernel<<<128, 256, 0, stream>>>(W1, W2, W1T, W2T);
    pool_kernel<<<B, 256, 0, stream>>>(node_feats, g_feats, degree, attn, seg_start, he);
    mlp_kernel<<<B / BM, 256, 0, stream>>>(he, W1T, b1, W2T, b2, g_feats, out);
}

// Round 5
// 112.194 us; speedup vs baseline: 1.4967x; 1.0025x over previous
//
#include <hip/hip_runtime.h>
#include <math.h>

#define H 256
#define NHD 4
#define BM 8

typedef float f32x4 __attribute__((ext_vector_type(4)));

// ---------------------------------------------------------------------------
// Fused prep: blocks 0..127 transpose W1/W2; blocks 128.. compute seg_start.
// seg is sorted; seg_start[b] = first node index with seg >= b, seg_start[B]=N
// ---------------------------------------------------------------------------
__global__ void prep_kernel(const int* __restrict__ seg,
                            int* __restrict__ seg_start,
                            int N, int B,
                            const float* __restrict__ W1,
                            const float* __restrict__ W2,
                            float* __restrict__ W1T,
                            float* __restrict__ W2T) {
    if (blockIdx.x < 128) {
        __shared__ float tile[32][33];
        const int which = blockIdx.x >> 6;
        const float* in = which ? W2 : W1;
        float* out = which ? W2T : W1T;
        const int blk = blockIdx.x & 63;
        const int bx = blk & 7, by = blk >> 3;
        const int tx = threadIdx.x & 31, ty = threadIdx.x >> 5;  // 32x8
#pragma unroll
        for (int r = 0; r < 32; r += 8)
            tile[ty + r][tx] = in[(by * 32 + ty + r) * H + bx * 32 + tx];
        __syncthreads();
#pragma unroll
        for (int r = 0; r < 32; r += 8)
            out[(bx * 32 + ty + r) * H + by * 32 + tx] = tile[tx][ty + r];
        return;
    }
    const int n = (blockIdx.x - 128) * blockDim.x + threadIdx.x;
    if (n >= N) return;
    const int s = seg[n];
    if (n == 0) {
        for (int b = 0; b <= s; ++b) seg_start[b] = 0;
    } else {
        const int sp = seg[n - 1];
        for (int b = sp + 1; b <= s; ++b) seg_start[b] = n;
    }
    if (n == N - 1) {
        for (int b = s + 1; b <= B; ++b) seg_start[b] = N;
    }
}

// ---------------------------------------------------------------------------
// Pool: one block (4 waves) per segment. Each wave: 8 consecutive node rows
// per iteration (8 KB in flight), 8-node mini-softmax, ONE online-softmax
// merge per 8 rows. Halves shuffle/exp/merge overhead per byte vs 4-row.
// Single pass over node_feats (nontemporal read-once stream).
// ---------------------------------------------------------------------------
__launch_bounds__(256, 6)
__global__ void pool_kernel(const float* __restrict__ node_feats,
                            const float* __restrict__ g_feats,
                            const float* __restrict__ degree,
                            const float* __restrict__ attn,
                            const int* __restrict__ seg_start,
                            float* __restrict__ he_out) {
    const int b = blockIdx.x;
    const int tid = threadIdx.x;
    const int wave = tid >> 6;
    const int lane = tid & 63;
    const int start = seg_start[b];
    const int end = seg_start[b + 1];

    const float4 g4 = *reinterpret_cast<const float4*>(g_feats + (size_t)b * H + lane * 4);
    const float4 a4 = *reinterpret_cast<const float4*>(attn + lane * 4);

    float gz = g4.x * a4.x + g4.y * a4.y + g4.z * a4.z + g4.w * a4.w;
#pragma unroll
    for (int s = 1; s < 16; s <<= 1) gz += __shfl_xor(gz, s, 64);

    float m = -INFINITY, lsum = 0.0f;
    float4 acc = make_float4(0.f, 0.f, 0.f, 0.f);

    int n0 = start + wave * 8;
    for (; n0 + 8 <= end; n0 += 32) {
        const float* rp = node_feats + (size_t)n0 * H + lane * 4;
        f32x4 v[8];
#pragma unroll
        for (int r = 0; r < 8; ++r)
            v[r] = __builtin_nontemporal_load(reinterpret_cast<const f32x4*>(rp + r * H));
        float d[8];
#pragma unroll
        for (int r = 0; r < 8; ++r) d[r] = degree[n0 + r];

        float p[8];
#pragma unroll
        for (int r = 0; r < 8; ++r)
            p[r] = v[r][0] * a4.x + v[r][1] * a4.y + v[r][2] * a4.z + v[r][3] * a4.w;
#pragma unroll
        for (int s = 1; s < 16; s <<= 1) {
#pragma unroll
            for (int r = 0; r < 8; ++r) p[r] += __shfl_xor(p[r], s, 64);
        }
        float z[8];
#pragma unroll
        for (int r = 0; r < 8; ++r) z[r] = (p[r] + gz) * d[r];

        // 8-node mini-softmax (parallel exps)
        float mz = z[0];
#pragma unroll
        for (int r = 1; r < 8; ++r) mz = fmaxf(mz, z[r]);
        float e[8], ls = 0.f;
#pragma unroll
        for (int r = 0; r < 8; ++r) { e[r] = __expf(z[r] - mz); ls += e[r]; }

        float ax = ls * g4.x, ay = ls * g4.y, az = ls * g4.z, aw = ls * g4.w;
#pragma unroll
        for (int r = 0; r < 8; ++r) {
            ax = __builtin_fmaf(e[r], v[r][0], ax);
            ay = __builtin_fmaf(e[r], v[r][1], ay);
            az = __builtin_fmaf(e[r], v[r][2], az);
            aw = __builtin_fmaf(e[r], v[r][3], aw);
        }

        // one merge per 8 rows
        const float mnew = fmaxf(m, mz);
        const float fo = __expf(m - mnew);   // 0 on first batch (m=-inf)
        const float fn = __expf(mz - mnew);
        lsum = lsum * fo + ls * fn;
        acc.x = acc.x * fo + ax * fn;
        acc.y = acc.y * fo + ay * fn;
        acc.z = acc.z * fo + az * fn;
        acc.w = acc.w * fo + aw * fn;
        m = mnew;
    }
    // remainder (<8 rows for this wave)
    const int nend = (n0 + 8 < end) ? (n0 + 8) : end;
    for (int n = n0; n < nend; ++n) {
        const float* rp = node_feats + (size_t)n * H + lane * 4;
        f32x4 v = __builtin_nontemporal_load(reinterpret_cast<const f32x4*>(rp));
        float p = v[0] * a4.x + v[1] * a4.y + v[2] * a4.z + v[3] * a4.w;
#pragma unroll
        for (int s = 1; s < 16; s <<= 1) p += __shfl_xor(p, s, 64);
        const float z = (p + gz) * degree[n];
        const float mnew = fmaxf(m, z);
        const float fo = __expf(m - mnew);
        const float e = __expf(z - mnew);
        lsum = lsum * fo + e;
        acc.x = acc.x * fo + e * (v[0] + g4.x);
        acc.y = acc.y * fo + e * (v[1] + g4.y);
        acc.z = acc.z * fo + e * (v[2] + g4.z);
        acc.w = acc.w * fo + e * (v[3] + g4.w);
        m = mnew;
    }

    // merge the 4 waves' (m, l, acc)
    __shared__ float sm[4][NHD];
    __shared__ float sl[4][NHD];
    __shared__ float sacc[4][H];
    const int head = lane >> 4;
    if ((lane & 15) == 0) { sm[wave][head] = m; sl[wave][head] = lsum; }
    *reinterpret_cast<float4*>(&sacc[wave][lane * 4]) = acc;
    __syncthreads();

    const int h = tid >> 6;
    float mstar = fmaxf(fmaxf(sm[0][h], sm[1][h]), fmaxf(sm[2][h], sm[3][h]));
    if (!(mstar > -INFINITY)) mstar = 0.0f;  // empty-segment guard
    float denom = 0.0f, hev = 0.0f;
#pragma unroll
    for (int w = 0; w < 4; ++w) {
        float fw = __expf(sm[w][h] - mstar);
        denom += sl[w][h] * fw;
        hev += sacc[w][tid] * fw;
    }
    he_out[(size_t)b * H + tid] = hev / fmaxf(denom, 1e-12f);
}

// ---------------------------------------------------------------------------
// MLP: wave q owns k-quarter [64q, 64q+64); thread (q,l) owns 4 output cols
// c = l + 64j for BM rows. Each broadcast ds_read_b128 feeds 16 FMAs.
// Cross-wave K reduction via 32KB LDS partials buffer.
// ---------------------------------------------------------------------------
__launch_bounds__(256, 4)
__global__ void mlp_kernel(const float* __restrict__ he,
                           const float* __restrict__ W1T,
                           const float* __restrict__ b1,
                           const float* __restrict__ W2T,
                           const float* __restrict__ b2,
                           const float* __restrict__ g_feats,
                           float* __restrict__ out) {
    __shared__ float hbuf[BM][H];       // 8 KB; holds he, then h1
    __shared__ float pacc[4][BM][H];    // 32 KB partials
    const int tid = threadIdx.x;
    const int q = tid >> 6;
    const int l = tid & 63;
    const size_t row0 = (size_t)blockIdx.x * BM;

#pragma unroll
    for (int i = 0; i < BM; ++i)
        hbuf[i][tid] = he[(row0 + i) * H + tid];
    __syncthreads();

#pragma unroll
    for (int layer = 0; layer < 2; ++layer) {
        const float* WT = layer ? W2T : W1T;
        float acc[BM][4];
#pragma unroll
        for (int i = 0; i < BM; ++i)
#pragma unroll
            for (int j = 0; j < 4; ++j) acc[i][j] = 0.f;

        const int k0 = q * 64;
        for (int s = 0; s < 64; s += 4) {
            const int k = k0 + s;
            float w[4][4];
#pragma unroll
            for (int kk = 0; kk < 4; ++kk)
#pragma unroll
                for (int j = 0; j < 4; ++j)
                    w[kk][j] = WT[(size_t)(k + kk) * H + l + 64 * j];
#pragma unroll
            for (int i = 0; i < BM; ++i) {
                const f32x4 hv = *reinterpret_cast<const f32x4*>(&hbuf[i][k]);
#pragma unroll
                for (int j = 0; j < 4; ++j) {
                    acc[i][j] = __builtin_fmaf(hv[0], w[0][j], acc[i][j]);
                    acc[i][j] = __builtin_fmaf(hv[1], w[1][j], acc[i][j]);
                    acc[i][j] = __builtin_fmaf(hv[2], w[2][j], acc[i][j]);
                    acc[i][j] = __builtin_fmaf(hv[3], w[3][j], acc[i][j]);
                }
            }
        }
#pragma unroll
        for (int i = 0; i < BM; ++i)
#pragma unroll
            for (int j = 0; j < 4; ++j)
                pacc[q][i][l + 64 * j] = acc[i][j];
        __syncthreads();

        const int i = tid >> 5;
        const int cbase = tid & 31;
        if (layer == 0) {
#pragma unroll
            for (int mm = 0; mm < 8; ++mm) {
                const int c = cbase + 32 * mm;
                float v = pacc[0][i][c] + pacc[1][i][c] + pacc[2][i][c] + pacc[3][i][c];
                hbuf[i][c] = fmaxf(v + b1[c], 0.f);
            }
        } else {
#pragma unroll
            for (int mm = 0; mm < 8; ++mm) {
                const int c = cbase + 32 * mm;
                float v = pacc[0][i][c] + pacc[1][i][c] + pacc[2][i][c] + pacc[3][i][c];
                out[(row0 + i) * H + c] = v + b2[c] + g_feats[(row0 + i) * H + c];
            }
        }
        __syncthreads();
    }
}

// ---------------------------------------------------------------------------
extern "C" void kernel_launch(void* const* d_in, const int* in_sizes, int n_in,
                              void* d_out, int out_size, void* d_ws, size_t ws_size,
                              hipStream_t stream) {
    const float* node_feats = (const float*)d_in[0];
    const float* g_feats    = (const float*)d_in[1];
    const float* degree     = (const float*)d_in[2];
    const int*   seg        = (const int*)d_in[3];
    const float* attn       = (const float*)d_in[4];
    const float* W1         = (const float*)d_in[5];
    const float* b1         = (const float*)d_in[6];
    const float* W2         = (const float*)d_in[7];
    const float* b2         = (const float*)d_in[8];
    float* out = (float*)d_out;

    const int N = in_sizes[3];
    const int B = in_sizes[1] / H;

    // workspace layout: seg_start needs (B+1)*4 = 16388 bytes -> reserve 32 KB
    char* ws = (char*)d_ws;
    int*   seg_start = (int*)ws;                         // 32 KB reserved
    float* W1T = (float*)(ws + 32768);                   // 256 KB
    float* W2T = (float*)(ws + 32768 + H * H * 4);       // 256 KB
    float* he  = (float*)(ws + 32768 + 2 * H * H * 4);   // 4 MB

    const int seg_blocks = (N + 255) / 256;
    prep_kernel<<<128 + seg_blocks, 256, 0, stream>>>(seg, seg_start, N, B, W1, W2, W1T, W2T);
    pool_kernel<<<B, 256, 0, stream>>>(node_feats, g_feats, degree, attn, seg_start, he);
    mlp_kernel<<<B / BM, 256, 0, stream>>>(he, W1T, b1, W2T, b2, g_feats, out);
}